// Round 16
// baseline (14910.887 us; speedup 1.0000x reference)
//
#include <hip/hip_runtime.h>
#include <hip/hip_fp16.h>
#include <math.h>

#define N_T 16384
#define S   128
#define S3  384
#define THREADS 256          // 4 waves, 1 per SIMD
#define L2E 1.4426950408889634f

typedef _Float16 half8 __attribute__((ext_vector_type(8)));
typedef float    f32x4 __attribute__((ext_vector_type(4)));

// native 2^x / 1/x where available; exact fallbacks keep compilation safe
#if __has_builtin(__builtin_amdgcn_exp2f)
#define EXP2(x) __builtin_amdgcn_exp2f(x)
#else
#define EXP2(x) exp2f(x)
#endif
#if __has_builtin(__builtin_amdgcn_rcpf)
#define RCP(x) __builtin_amdgcn_rcpf(x)
#else
#define RCP(x) (1.0f / (x))
#endif

// raw barrier: LDS-visibility only (NO vmcnt drain -> in-flight global loads
// can cross barriers freely, unlike __syncthreads()).
#define BAR() do { \
    asm volatile("s_waitcnt lgkmcnt(0)" ::: "memory"); \
    __builtin_amdgcn_s_barrier();                      \
    asm volatile("" ::: "memory");                     \
} while (0)

// ---------------------------------------------------------------------------
// Kernel 0: fold proj into w_ih (fp32). b_ih + r/z parts of b_hh folded;
// n-part of b_hh stays separate (scaled by r). gi columns carry the exp2
// prescale IN FP32: log2e (r,z rows), 2*log2e (n rows).
// ---------------------------------------------------------------------------
__global__ void prep_kernel(const float* __restrict__ w_ih,
                            const float* __restrict__ b_ih,
                            const float* __restrict__ b_hh,
                            const float* __restrict__ proj_w,
                            const float* __restrict__ proj_b,
                            float* __restrict__ Mt,
                            float* __restrict__ b2,
                            float* __restrict__ mc) {
    int j = blockIdx.x;    // 0..383
    int m = threadIdx.x;   // 0..127
    const float sc = (j < 2 * S) ? L2E : 2.f * L2E;
    float acc = 0.f;
    for (int k = 0; k < S - 1; ++k)
        acc += w_ih[j * S + k] * proj_w[k * S + m];
    Mt[m * S3 + j] = acc * sc;
    if (m == 0) {
        float a = 0.f;
        for (int k = 0; k < S - 1; ++k) a += w_ih[j * S + k] * proj_b[k];
        b2[j] = (b_ih[j] + ((j < 2 * S) ? b_hh[j] : 0.f) + a) * sc;
        mc[j] = w_ih[j * S + (S - 1)] * sc;
    }
}

// ---------------------------------------------------------------------------
// Kernel 0b: w_hh as packed f16 pairs, CONTIGUOUS pairing, UNSCALED (exact
// verified weight realization). Word i of row j = (w[j][2i], w[j][2i+1]) --
// serves the dot2 rows, the MFMA A-fragments, and the fallback.
// ---------------------------------------------------------------------------
__global__ void wcvt_kernel(const float* __restrict__ w_hh,
                            unsigned* __restrict__ Whh16) {
    int j = blockIdx.x;    // row 0..383
    int m = threadIdx.x;   // word 0..63
    __half2 p = __floats2half2_rn(w_hh[j * S + 2 * m], w_hh[j * S + 2 * m + 1]);
    Whh16[j * 64 + m] = *(unsigned*)&p;
}

// ---------------------------------------------------------------------------
// Kernel 1: gi[t][j] = b2[j] + dot(evs[t], M[j]) + (t==0 ? mc[j] : 0)  (fp32)
// ---------------------------------------------------------------------------
#define TB 32
__global__ void gi_kernel(const float* __restrict__ evs,
                          const float* __restrict__ Mt,
                          const float* __restrict__ b2,
                          const float* __restrict__ mc,
                          float* __restrict__ gi) {
    int j  = threadIdx.x;        // 0..383
    int t0 = blockIdx.x * TB;

    float mcol[S];
#pragma unroll
    for (int k = 0; k < S; ++k) mcol[k] = Mt[k * S3 + j];

    __shared__ float ev[TB][S];
    for (int i = j; i < TB * S; i += S3)
        ev[i / S][i % S] = evs[t0 * S + i];
    __syncthreads();

    float bb  = b2[j];
    float mcj = mc[j];
    for (int tt = 0; tt < TB; ++tt) {
        int t = t0 + tt;
        float acc = bb + ((t == 0) ? mcj : 0.f);
#pragma unroll
        for (int k = 0; k < S; ++k) acc += ev[tt][k] * mcol[k];
        gi[t * S3 + j] = acc;
    }
}

// ---------------------------------------------------------------------------
// Kernel 2: sequential GRU scan. 1 workgroup, 256 threads = 4 waves (1/SIMD).
//
// R16 = hybrid MFMA+dot2: both matvec engines run concurrently IN ONE WAVE.
// Evidence: 24 MFMAs cost ~380cy/SIMD/step at ANY wave arrangement (R13 vs
// R15 counters) -> ~16cy cadence with ~12 free issue slots per MFMA; dot2
// rows are INDEPENDENT of the MFMA accumulators, so they legally fill those
// slots (R14 failed only because its inserted VALU depended on the MFMAs).
//   Wave c owns gate rows 32c..32c+31:
//     rows 32c+0..15  via 12 MFMAs (3 gate C-tiles x 4 K-chunks,
//       broadcast-B, R13/R15-verified layout + 3-cndmask select);
//     rows 32c+16..31 via 48 dot2 (R12-verified quarter-split: lane quarter
//       kq = l>>4 takes k-words [16kq,16kq+16), sequential d0/d1/d2
//       accumulators, 2-stage shfl_xor combine).
//   Each lane computes TWO gate-rows (rrM 4x-dup, rrD 4x-dup); writers
//   (l&15)<4 and l<16 publish the 32 h values. Same verified gate math /
//   h16 double-buffer / 1 BAR per step / gi register pipeline (now 6
//   streams). Self-test retained; fallback = VERBATIM verified R10 loop.
// ---------------------------------------------------------------------------
#define DOT2(acc, wreg, hreg_) \
    asm("v_dot2_f32_f16 %0, %1, %2, %0" : "+v"(acc) : "v"(wreg), "v"(hreg_));

__global__ __attribute__((amdgpu_flat_work_group_size(THREADS, THREADS),
                          amdgpu_waves_per_eu(1, 1))) void
scan_kernel(const float* __restrict__ gi,
            const unsigned* __restrict__ Whh16,
            const float* __restrict__ h0,
            const float* __restrict__ b_hh,
            const float* __restrict__ final_w,
            const float* __restrict__ final_b,
            float* __restrict__ out) {
    const int tid = threadIdx.x;
    const int l   = tid & 63;
    const int c   = tid >> 6;           // wave 0..3

    __shared__ __align__(16) unsigned h16[2][64];   // (h[2i],h[2i+1]) pairs
    __shared__ float hfin[S];

    // ---- MFMA layout self-test (registers only; wave-uniform verdict) ----
    bool usemfma;
    {
        const int g4 = l >> 4;
        half8 ta, tb;
#pragma unroll
        for (int i = 0; i < 8; ++i) {
            int k = 8 * g4 + i;
            ta[i] = (_Float16)(float)((l & 15) * 32 + k);
            tb[i] = (k == 5) ? (_Float16)1.f : (_Float16)0.f;
        }
        f32x4 tc = {0.f, 0.f, 0.f, 0.f};
        tc = __builtin_amdgcn_mfma_f32_16x16x32_f16(ta, tb, tc, 0, 0, 0);
        bool ok = true;
#pragma unroll
        for (int rg = 0; rg < 4; ++rg)
            ok = ok && (tc[rg] == (float)((4 * g4 + rg) * 32 + 5));
        usemfma = (bool)__all((int)ok);
    }

    if (usemfma) {
        // ================= hybrid MFMA + dot2 path =================
        const int g4  = l >> 4;             // lane 16-group == k-quarter
        const int p   = l & 3;              // C-reg selector
        const int rrM = (c << 5) + (g4 << 2) + p;        // MFMA gate row
        const int rrD = (c << 5) + 16 + (l & 15);        // dot2 gate row
        const int kw0 = g4 << 4;            // dot2 first k-word
        const bool wM = (l & 15) < 4;
        const bool wD = l < 16;
        const bool s0 = (p & 1) != 0, s1 = (p & 2) != 0;

        // MFMA A fragments: gate m, K-chunk q; W row j = 128m + 32c + (l&15)
        half8 a[3][4];
#pragma unroll
        for (int m = 0; m < 3; ++m) {
            const int j = 128 * m + 32 * c + (l & 15);
            const unsigned* rowp = Whh16 + (size_t)j * 64 + 4 * g4;
#pragma unroll
            for (int q = 0; q < 4; ++q)
                a[m][q] = *(const half8*)(rowp + 16 * q);
        }
        // dot2 weights: W rows {0,128,256} + rrD's base, words [kw0,kw0+16)
        unsigned w0[16], w1[16], w2[16];
        {
            const int jD = 32 * c + 16 + (l & 15);
            const unsigned* pw = Whh16 + (size_t)jD * 64 + kw0;
#pragma unroll
            for (int i = 0; i < 16; ++i) {
                w0[i] = pw[i];
                w1[i] = pw[i + 128 * 64];
                w2[i] = pw[i + 256 * 64];
            }
        }

        float bnM = b_hh[2 * S + rrM] * (2.f * L2E);
        float bnD = b_hh[2 * S + rrD] * (2.f * L2E);
        float hM  = h0[rrM];
        float hD  = h0[rrD];
        if (wM) ((unsigned short*)&h16[0][0])[rrM] =
                    __half_as_ushort(__float2half(hM));
        if (wD) ((unsigned short*)&h16[0][0])[rrD] =
                    __half_as_ushort(__float2half(hD));

        // gi register pipeline, depth 4, 6 streams (both rows)
        float gMr[4], gMz[4], gMn[4], gDr[4], gDz[4], gDn[4];
#pragma unroll
        for (int u = 0; u < 4; ++u) {
            gMr[u] = gi[(size_t)u * S3 + rrM];
            gMz[u] = gi[(size_t)u * S3 + rrM + S];
            gMn[u] = gi[(size_t)u * S3 + rrM + 2 * S];
            gDr[u] = gi[(size_t)u * S3 + rrD];
            gDz[u] = gi[(size_t)u * S3 + rrD + S];
            gDn[u] = gi[(size_t)u * S3 + rrD + 2 * S];
        }
        BAR();   // h16[0] visible

        for (int t = 0; t < N_T; t += 4) {
#pragma unroll
            for (int u = 0; u < 4; ++u) {
                const int tt = t + u;
                // h reads: MFMA broadcast-B frags + dot2 quarter words
                const half8* hb = (const half8*)&h16[u & 1][0];
                half8 b[4];
#pragma unroll
                for (int q = 0; q < 4; ++q) b[q] = hb[4 * q + g4];
                const uint4* hp = (const uint4*)&h16[u & 1][kw0];
                uint4 qd[4];
#pragma unroll
                for (int i = 0; i < 4; ++i) qd[i] = hp[i];

                // gi consume + early refill (VMEM flies under compute)
                const float mr = gMr[u], mz = gMz[u], mn = gMn[u];
                const float dr = gDr[u], dz = gDz[u], dn = gDn[u];
                if (tt + 4 < N_T) {
                    gMr[u] = gi[(size_t)(tt + 4) * S3 + rrM];
                    gMz[u] = gi[(size_t)(tt + 4) * S3 + rrM + S];
                    gMn[u] = gi[(size_t)(tt + 4) * S3 + rrM + 2 * S];
                    gDr[u] = gi[(size_t)(tt + 4) * S3 + rrD];
                    gDz[u] = gi[(size_t)(tt + 4) * S3 + rrD + S];
                    gDn[u] = gi[(size_t)(tt + 4) * S3 + rrD + 2 * S];
                }

                // merged compute: MFMAs (matrix pipe) interleaved with
                // INDEPENDENT dot2s (VALU pipe) -- fills the MFMA cadence
                f32x4 cr = {0.f, 0.f, 0.f, 0.f}, cz = cr, cn = cr;
                float d0 = 0.f, d1 = 0.f, d2 = 0.f;
#pragma unroll
                for (int q = 0; q < 4; ++q) {
                    cr = __builtin_amdgcn_mfma_f32_16x16x32_f16(a[0][q], b[q], cr, 0, 0, 0);
                    cz = __builtin_amdgcn_mfma_f32_16x16x32_f16(a[1][q], b[q], cz, 0, 0, 0);
                    cn = __builtin_amdgcn_mfma_f32_16x16x32_f16(a[2][q], b[q], cn, 0, 0, 0);
                    const unsigned hw[4] = { qd[q].x, qd[q].y, qd[q].z, qd[q].w };
#pragma unroll
                    for (int jj = 0; jj < 4; ++jj) {
                        const int idx = 4 * q + jj;
                        DOT2(d0, w0[idx], hw[jj])
                        DOT2(d1, w1[idx], hw[jj])
                        DOT2(d2, w2[idx], hw[jj])
                    }
                }

                // dot2 combine (R12-verified 2-stage shfl)
                d0 += __shfl_xor(d0, 16, 64);
                d1 += __shfl_xor(d1, 16, 64);
                d2 += __shfl_xor(d2, 16, 64);
                d0 += __shfl_xor(d0, 32, 64);
                d1 += __shfl_xor(d1, 32, 64);
                d2 += __shfl_xor(d2, 32, 64);

                // MFMA select (R15-verified)
                float a0 = s1 ? (s0 ? cr.w : cr.z) : (s0 ? cr.y : cr.x);
                float a1 = s1 ? (s0 ? cz.w : cz.z) : (s0 ? cz.y : cz.x);
                float a2 = s1 ? (s0 ? cn.w : cn.z) : (s0 ? cn.y : cn.x);

                // gate for MFMA row
                {
                    float r = RCP(1.f + EXP2(-__builtin_fmaf(L2E, a0, mr)));
                    float z = RCP(1.f + EXP2(-__builtin_fmaf(L2E, a1, mz)));
                    float e = EXP2(__builtin_fmaf(
                                  r, __builtin_fmaf(2.f * L2E, a2, bnM), mn));
                    float n = 1.f - 2.f * RCP(e + 1.f);
                    hM = n + z * (hM - n);
                }
                // gate for dot2 row
                {
                    float r = RCP(1.f + EXP2(-__builtin_fmaf(L2E, d0, dr)));
                    float z = RCP(1.f + EXP2(-__builtin_fmaf(L2E, d1, dz)));
                    float e = EXP2(__builtin_fmaf(
                                  r, __builtin_fmaf(2.f * L2E, d2, bnD), dn));
                    float n = 1.f - 2.f * RCP(e + 1.f);
                    hD = n + z * (hD - n);
                }

                if (wM) ((unsigned short*)&h16[(u & 1) ^ 1][0])[rrM] =
                            __half_as_ushort(__float2half(hM));
                if (wD) ((unsigned short*)&h16[(u & 1) ^ 1][0])[rrD] =
                            __half_as_ushort(__float2half(hD));

                BAR();
            }
        }
        if (wM) hfin[rrM] = hM;
        if (wD) hfin[rrD] = hD;
    } else {
        // ================= fallback: VERBATIM verified R10 loop =============
        const int lh  = l & 31;
        const int Rh  = (c << 5) + lh;
        const int kw0 = (l & 32);

        unsigned w0[32], w1[32], w2[32];
        {
            const unsigned* pw = Whh16 + (size_t)Rh * 64 + kw0;
#pragma unroll
            for (int i = 0; i < 32; ++i) {
                w0[i] = pw[i];
                w1[i] = pw[i + 128 * 64];
                w2[i] = pw[i + 256 * 64];
            }
        }

        float bn2  = b_hh[2 * S + Rh] * (2.f * L2E);
        float hreg = h0[Rh];
        if (l < 32)
            ((unsigned short*)&h16[0][0])[Rh] =
                __half_as_ushort(__float2half(hreg));

        float gpr[4], gpz[4], gpn[4];
#pragma unroll
        for (int u = 0; u < 4; ++u) {
            gpr[u] = gi[(size_t)u * S3 + Rh];
            gpz[u] = gi[(size_t)u * S3 + Rh + S];
            gpn[u] = gi[(size_t)u * S3 + Rh + 2 * S];
        }
        BAR();

        for (int t = 0; t < N_T; t += 4) {
#pragma unroll
            for (int u = 0; u < 4; ++u) {
                const int tt = t + u;
                const uint4* hp = (const uint4*)&h16[u & 1][kw0];
                uint4 q[8];
#pragma unroll
                for (int i = 0; i < 8; ++i) q[i] = hp[i];

                float a0 = 0.f, a1 = 0.f, a2 = 0.f;
#pragma unroll
                for (int i = 0; i < 8; ++i) {
                    const unsigned hw[4] = { q[i].x, q[i].y, q[i].z, q[i].w };
#pragma unroll
                    for (int jj2 = 0; jj2 < 4; ++jj2) {
                        const int idx = 4 * i + jj2;
                        DOT2(a0, w0[idx], hw[jj2])
                        DOT2(a1, w1[idx], hw[jj2])
                        DOT2(a2, w2[idx], hw[jj2])
                    }
                }
                a0 += __shfl_xor(a0, 32, 64);
                a1 += __shfl_xor(a1, 32, 64);
                a2 += __shfl_xor(a2, 32, 64);

                float r  = RCP(1.f + EXP2(-__builtin_fmaf(L2E, a0, gpr[u])));
                float z  = RCP(1.f + EXP2(-__builtin_fmaf(L2E, a1, gpz[u])));
                float e  = EXP2(__builtin_fmaf(
                               r, __builtin_fmaf(2.f * L2E, a2, bn2), gpn[u]));
                float n  = 1.f - 2.f * RCP(e + 1.f);
                hreg = n + z * (hreg - n);

                if (l < 32)
                    ((unsigned short*)&h16[(u & 1) ^ 1][0])[Rh] =
                        __half_as_ushort(__float2half(hreg));

                if (tt + 4 < N_T) {
                    gpr[u] = gi[(size_t)(tt + 4) * S3 + Rh];
                    gpz[u] = gi[(size_t)(tt + 4) * S3 + Rh + S];
                    gpn[u] = gi[(size_t)(tt + 4) * S3 + Rh + 2 * S];
                }

                BAR();
            }
        }
        if (l < 32) hfin[Rh] = hreg;
    }

    // common epilogue: out = h @ final_w.T + final_b
    BAR();
    if (tid < 3) {
        float acc = final_b[tid];
        for (int k = 0; k < S; ++k) acc += final_w[tid * S + k] * hfin[k];
        out[tid] = acc;
    }
}

// ---------------------------------------------------------------------------
extern "C" void kernel_launch(void* const* d_in, const int* in_sizes, int n_in,
                              void* d_out, int out_size, void* d_ws, size_t ws_size,
                              hipStream_t stream) {
    const float* evs     = (const float*)d_in[0];
    const float* h0      = (const float*)d_in[1];
    const float* w_ih    = (const float*)d_in[2];
    const float* w_hh    = (const float*)d_in[3];
    const float* b_ih    = (const float*)d_in[4];
    const float* b_hh    = (const float*)d_in[5];
    const float* proj_w  = (const float*)d_in[6];
    const float* proj_b  = (const float*)d_in[7];
    const float* final_w = (const float*)d_in[8];
    const float* final_b = (const float*)d_in[9];
    float* out = (float*)d_out;

    // workspace layout (floats)
    float* gi = (float*)d_ws;                  // N_T * 384
    float* Mt = gi + (size_t)N_T * S3;         // 128 * 384
    float* b2 = Mt + (size_t)S * S3;           // 384
    float* mc = b2 + S3;                       // 384
    unsigned* Whh16 = (unsigned*)(mc + S3);    // 384 * 64 packed f16 pairs

    prep_kernel<<<S3, S, 0, stream>>>(w_ih, b_ih, b_hh, proj_w, proj_b, Mt, b2, mc);
    wcvt_kernel<<<S3, 64, 0, stream>>>(w_hh, Whh16);
    gi_kernel<<<N_T / TB, S3, 0, stream>>>(evs, Mt, b2, mc, gi);
    scan_kernel<<<1, THREADS, 0, stream>>>(gi, Whh16, h0, b_hh,
                                           final_w, final_b, out);
}

// Round 17
// 6958.936 us; speedup vs baseline: 2.1427x; 2.1427x over previous
//
#include <hip/hip_runtime.h>
#include <hip/hip_fp16.h>
#include <math.h>

#define N_T 16384
#define S   128
#define S3  384
#define THREADS 256          // 4 waves, 1 per SIMD
#define L2E 1.4426950408889634f

typedef _Float16 half8 __attribute__((ext_vector_type(8)));
typedef float    f32x4 __attribute__((ext_vector_type(4)));

// native 2^x / 1/x where available; exact fallbacks keep compilation safe
#if __has_builtin(__builtin_amdgcn_exp2f)
#define EXP2(x) __builtin_amdgcn_exp2f(x)
#else
#define EXP2(x) exp2f(x)
#endif
#if __has_builtin(__builtin_amdgcn_rcpf)
#define RCP(x) __builtin_amdgcn_rcpf(x)
#else
#define RCP(x) (1.0f / (x))
#endif

// raw barrier: LDS-visibility only (NO vmcnt drain -> in-flight global loads
// can cross barriers freely, unlike __syncthreads()).
#define BAR() do { \
    asm volatile("s_waitcnt lgkmcnt(0)" ::: "memory"); \
    __builtin_amdgcn_s_barrier();                      \
    asm volatile("" ::: "memory");                     \
} while (0)

// ---------------------------------------------------------------------------
// Kernel 0: fold proj into w_ih (fp32). b_ih + r/z parts of b_hh folded;
// n-part of b_hh stays separate (scaled by r). gi columns carry the exp2
// prescale IN FP32: log2e (r,z rows), 2*log2e (n rows).
// ---------------------------------------------------------------------------
__global__ void prep_kernel(const float* __restrict__ w_ih,
                            const float* __restrict__ b_ih,
                            const float* __restrict__ b_hh,
                            const float* __restrict__ proj_w,
                            const float* __restrict__ proj_b,
                            float* __restrict__ Mt,
                            float* __restrict__ b2,
                            float* __restrict__ mc) {
    int j = blockIdx.x;    // 0..383
    int m = threadIdx.x;   // 0..127
    const float sc = (j < 2 * S) ? L2E : 2.f * L2E;
    float acc = 0.f;
    for (int k = 0; k < S - 1; ++k)
        acc += w_ih[j * S + k] * proj_w[k * S + m];
    Mt[m * S3 + j] = acc * sc;
    if (m == 0) {
        float a = 0.f;
        for (int k = 0; k < S - 1; ++k) a += w_ih[j * S + k] * proj_b[k];
        b2[j] = (b_ih[j] + ((j < 2 * S) ? b_hh[j] : 0.f) + a) * sc;
        mc[j] = w_ih[j * S + (S - 1)] * sc;
    }
}

// ---------------------------------------------------------------------------
// Kernel 0b: w_hh as packed f16 pairs, CONTIGUOUS pairing, UNSCALED (exact
// verified weight realization). Word i of row j = (w[j][2i], w[j][2i+1]) --
// serves both the dot2 fallback and the MFMA A-fragments.
// ---------------------------------------------------------------------------
__global__ void wcvt_kernel(const float* __restrict__ w_hh,
                            unsigned* __restrict__ Whh16) {
    int j = blockIdx.x;    // row 0..383
    int m = threadIdx.x;   // word 0..63
    __half2 p = __floats2half2_rn(w_hh[j * S + 2 * m], w_hh[j * S + 2 * m + 1]);
    Whh16[j * 64 + m] = *(unsigned*)&p;
}

// ---------------------------------------------------------------------------
// Kernel 1: gi[t][j] = b2[j] + dot(evs[t], M[j]) + (t==0 ? mc[j] : 0)  (fp32)
// R17: ev read from LDS as float4 (4x fewer DS instrs); summation stays in
// exact k-order -> bit-identical to the verified scalar version.
// ---------------------------------------------------------------------------
#define TB 32
__global__ void gi_kernel(const float* __restrict__ evs,
                          const float* __restrict__ Mt,
                          const float* __restrict__ b2,
                          const float* __restrict__ mc,
                          float* __restrict__ gi) {
    int j  = threadIdx.x;        // 0..383
    int t0 = blockIdx.x * TB;

    float mcol[S];
#pragma unroll
    for (int k = 0; k < S; ++k) mcol[k] = Mt[k * S3 + j];

    __shared__ __align__(16) float ev[TB][S];
    {
        const float4* src = (const float4*)(evs + (size_t)t0 * S);
        float4* dst = (float4*)(&ev[0][0]);
        for (int i = j; i < TB * S / 4; i += S3) dst[i] = src[i];
    }
    __syncthreads();

    float bb  = b2[j];
    float mcj = mc[j];
    for (int tt = 0; tt < TB; ++tt) {
        int t = t0 + tt;
        float acc = bb + ((t == 0) ? mcj : 0.f);
        const float4* evp = (const float4*)(&ev[tt][0]);
#pragma unroll
        for (int k4 = 0; k4 < S / 4; ++k4) {
            float4 v = evp[k4];
            acc += v.x * mcol[4 * k4 + 0];
            acc += v.y * mcol[4 * k4 + 1];
            acc += v.z * mcol[4 * k4 + 2];
            acc += v.w * mcol[4 * k4 + 3];
        }
        gi[t * S3 + j] = acc;
    }
}

// ---------------------------------------------------------------------------
// Kernel 2: sequential GRU scan. 1 workgroup, 256 threads = 4 waves (1/SIMD).
//
// R17 = VERBATIM revert to the verified R13 kernel (best: 6294us scan,
// absmax 0.0). Floor characterization (R13-R16 counters):
//   step ~922cy = B-read ~120 (post-barrier LDS latency; h produced right
//   before the barrier, irreducible) + MFMA ~382 (hard matrix-pipe
//   throughput: 16x16x32-f16 ~16cy/SIMD at ANY wave arrangement, R13=R15)
//   + select+gate ~200 (serial trans chain, rcp/exp2-optimized) + write/
//   barrier/skew ~220. Overlap probes all regress: intra-wave phasing
//   (R14: in-order issue serializes), multi-wave (R12/R15: pipe is
//   throughput-shared + VALU collision), MFMA+dot2 hybrid (R16: pipe-
//   transition hazards). Matvec-on-MFMA's 16x column waste is structural
//   (serial h dependence forbids time-batching).
// ---------------------------------------------------------------------------
#define DOT2(acc, wreg, hreg_) \
    asm("v_dot2_f32_f16 %0, %1, %2, %0" : "+v"(acc) : "v"(wreg), "v"(hreg_));

__global__ __attribute__((amdgpu_flat_work_group_size(THREADS, THREADS),
                          amdgpu_waves_per_eu(1, 1))) void
scan_kernel(const float* __restrict__ gi,
            const unsigned* __restrict__ Whh16,
            const float* __restrict__ h0,
            const float* __restrict__ b_hh,
            const float* __restrict__ final_w,
            const float* __restrict__ final_b,
            float* __restrict__ out) {
    const int tid = threadIdx.x;
    const int l   = tid & 63;
    const int c   = tid >> 6;           // wave 0..3

    __shared__ __align__(16) unsigned h16[2][64];   // (h[2i],h[2i+1]) pairs
    __shared__ float hfin[S];

    // ---- MFMA layout self-test (registers only; block-uniform verdict) ----
    // Assumed: A row = l&15, A k = 8*(l>>4)+i ; B k = 8*(l>>4)+i ;
    //          C col = l&15, C row = (l>>4)*4 + reg.
    bool usemfma;
    {
        const int g4 = l >> 4;
        half8 ta, tb;
#pragma unroll
        for (int i = 0; i < 8; ++i) {
            int k = 8 * g4 + i;
            ta[i] = (_Float16)(float)((l & 15) * 32 + k);
            tb[i] = (k == 5) ? (_Float16)1.f : (_Float16)0.f;
        }
        f32x4 tc = {0.f, 0.f, 0.f, 0.f};
        tc = __builtin_amdgcn_mfma_f32_16x16x32_f16(ta, tb, tc, 0, 0, 0);
        bool ok = true;
#pragma unroll
        for (int rg = 0; rg < 4; ++rg)
            ok = ok && (tc[rg] == (float)((4 * g4 + rg) * 32 + 5));
        usemfma = (bool)__all((int)ok);
    }

    if (usemfma) {
        // ================= MFMA path (verified R13) =================
        const int g4 = l >> 4;              // lane 16-group
        const int p  = l & 7;               // gate-row selector
        const int jj = 4 * g4 + (p & 3) + ((p & 4) ? 16 : 0);
        const int rr = (c << 5) + jj;       // owned gate row 0..127
        const bool writer = (l & 15) < 8;   // one writer per row
        const bool s0 = (p & 1) != 0, s1 = (p & 2) != 0, s2 = (p & 4) != 0;

        // A fragments: tile m = [r-lo,r-hi,z-lo,z-hi,n-lo,n-hi], K-chunk q.
        half8 a[6][4];
#pragma unroll
        for (int m = 0; m < 6; ++m) {
            const int j = 128 * (m >> 1) + 32 * c + 16 * (m & 1) + (l & 15);
            const unsigned* rowp = Whh16 + (size_t)j * 64 + 4 * g4;
#pragma unroll
            for (int q = 0; q < 4; ++q)
                a[m][q] = *(const half8*)(rowp + 16 * q);
        }

        float bn2  = b_hh[2 * S + rr] * (2.f * L2E);
        float hreg = h0[rr];
        if (writer)
            ((unsigned short*)&h16[0][0])[rr] =
                __half_as_ushort(__float2half(hreg));

        float gpr[4], gpz[4], gpn[4];
#pragma unroll
        for (int u = 0; u < 4; ++u) {
            gpr[u] = gi[(size_t)u * S3 + rr];
            gpz[u] = gi[(size_t)u * S3 + rr + S];
            gpn[u] = gi[(size_t)u * S3 + rr + 2 * S];
        }
        BAR();   // h16[0] visible

        for (int t = 0; t < N_T; t += 4) {
#pragma unroll
            for (int u = 0; u < 4; ++u) {
                const int tt = t + u;
                // broadcast-B: lane half i = h[32q + 8*g4 + i]
                const half8* hb = (const half8*)&h16[u & 1][0];
                half8 b[4];
#pragma unroll
                for (int q = 0; q < 4; ++q) b[q] = hb[4 * q + g4];

                f32x4 cc[6];
#pragma unroll
                for (int m = 0; m < 6; ++m) cc[m] = (f32x4){0.f, 0.f, 0.f, 0.f};
#pragma unroll
                for (int q = 0; q < 4; ++q)
#pragma unroll
                    for (int m = 0; m < 6; ++m)
                        cc[m] = __builtin_amdgcn_mfma_f32_16x16x32_f16(
                                    a[m][q], b[q], cc[m], 0, 0, 0);

                // register select: row jj -> tile half (s2), reg (s0,s1)
                f32x4 t0v = s2 ? cc[1] : cc[0];
                f32x4 t1v = s2 ? cc[3] : cc[2];
                f32x4 t2v = s2 ? cc[5] : cc[4];
                float a0 = s1 ? (s0 ? t0v.w : t0v.z) : (s0 ? t0v.y : t0v.x);
                float a1 = s1 ? (s0 ? t1v.w : t1v.z) : (s0 ? t1v.y : t1v.x);
                float a2 = s1 ? (s0 ? t2v.w : t2v.z) : (s0 ? t2v.y : t2v.x);

                // gates: verified R10 math (native 2^x, v_rcp)
                float r  = RCP(1.f + EXP2(-__builtin_fmaf(L2E, a0, gpr[u])));
                float z  = RCP(1.f + EXP2(-__builtin_fmaf(L2E, a1, gpz[u])));
                float e  = EXP2(__builtin_fmaf(
                               r, __builtin_fmaf(2.f * L2E, a2, bn2), gpn[u]));
                float n  = 1.f - 2.f * RCP(e + 1.f);   // tanh
                hreg = n + z * (hreg - n);

                if (writer)
                    ((unsigned short*)&h16[(u & 1) ^ 1][0])[rr] =
                        __half_as_ushort(__float2half(hreg));

                // refill this gi slot for step tt+4 (vmem, flies across BAR)
                if (tt + 4 < N_T) {
                    gpr[u] = gi[(size_t)(tt + 4) * S3 + rr];
                    gpz[u] = gi[(size_t)(tt + 4) * S3 + rr + S];
                    gpn[u] = gi[(size_t)(tt + 4) * S3 + rr + 2 * S];
                }

                BAR();
            }
        }
        if (writer) hfin[rr] = hreg;
    } else {
        // ================= fallback: VERBATIM verified R10 loop =============
        const int lh  = l & 31;
        const int Rh  = (c << 5) + lh;
        const int kw0 = (l & 32);

        unsigned w0[32], w1[32], w2[32];
        {
            const unsigned* pw = Whh16 + (size_t)Rh * 64 + kw0;
#pragma unroll
            for (int i = 0; i < 32; ++i) {
                w0[i] = pw[i];
                w1[i] = pw[i + 128 * 64];
                w2[i] = pw[i + 256 * 64];
            }
        }

        float bn2  = b_hh[2 * S + Rh] * (2.f * L2E);
        float hreg = h0[Rh];
        if (l < 32)
            ((unsigned short*)&h16[0][0])[Rh] =
                __half_as_ushort(__float2half(hreg));

        float gpr[4], gpz[4], gpn[4];
#pragma unroll
        for (int u = 0; u < 4; ++u) {
            gpr[u] = gi[(size_t)u * S3 + Rh];
            gpz[u] = gi[(size_t)u * S3 + Rh + S];
            gpn[u] = gi[(size_t)u * S3 + Rh + 2 * S];
        }
        BAR();

        for (int t = 0; t < N_T; t += 4) {
#pragma unroll
            for (int u = 0; u < 4; ++u) {
                const int tt = t + u;
                const uint4* hp = (const uint4*)&h16[u & 1][kw0];
                uint4 q[8];
#pragma unroll
                for (int i = 0; i < 8; ++i) q[i] = hp[i];

                float a0 = 0.f, a1 = 0.f, a2 = 0.f;
#pragma unroll
                for (int i = 0; i < 8; ++i) {
                    const unsigned hw[4] = { q[i].x, q[i].y, q[i].z, q[i].w };
#pragma unroll
                    for (int jj2 = 0; jj2 < 4; ++jj2) {
                        const int idx = 4 * i + jj2;
                        DOT2(a0, w0[idx], hw[jj2])
                        DOT2(a1, w1[idx], hw[jj2])
                        DOT2(a2, w2[idx], hw[jj2])
                    }
                }
                a0 += __shfl_xor(a0, 32, 64);
                a1 += __shfl_xor(a1, 32, 64);
                a2 += __shfl_xor(a2, 32, 64);

                float r  = RCP(1.f + EXP2(-__builtin_fmaf(L2E, a0, gpr[u])));
                float z  = RCP(1.f + EXP2(-__builtin_fmaf(L2E, a1, gpz[u])));
                float e  = EXP2(__builtin_fmaf(
                               r, __builtin_fmaf(2.f * L2E, a2, bn2), gpn[u]));
                float n  = 1.f - 2.f * RCP(e + 1.f);
                hreg = n + z * (hreg - n);

                if (l < 32)
                    ((unsigned short*)&h16[(u & 1) ^ 1][0])[Rh] =
                        __half_as_ushort(__float2half(hreg));

                if (tt + 4 < N_T) {
                    gpr[u] = gi[(size_t)(tt + 4) * S3 + Rh];
                    gpz[u] = gi[(size_t)(tt + 4) * S3 + Rh + S];
                    gpn[u] = gi[(size_t)(tt + 4) * S3 + Rh + 2 * S];
                }

                BAR();
            }
        }
        if (l < 32) hfin[Rh] = hreg;
    }

    // common epilogue: out = h @ final_w.T + final_b
    BAR();
    if (tid < 3) {
        float acc = final_b[tid];
        for (int k = 0; k < S; ++k) acc += final_w[tid * S + k] * hfin[k];
        out[tid] = acc;
    }
}

// ---------------------------------------------------------------------------
extern "C" void kernel_launch(void* const* d_in, const int* in_sizes, int n_in,
                              void* d_out, int out_size, void* d_ws, size_t ws_size,
                              hipStream_t stream) {
    const float* evs     = (const float*)d_in[0];
    const float* h0      = (const float*)d_in[1];
    const float* w_ih    = (const float*)d_in[2];
    const float* w_hh    = (const float*)d_in[3];
    const float* b_ih    = (const float*)d_in[4];
    const float* b_hh    = (const float*)d_in[5];
    const float* proj_w  = (const float*)d_in[6];
    const float* proj_b  = (const float*)d_in[7];
    const float* final_w = (const float*)d_in[8];
    const float* final_b = (const float*)d_in[9];
    float* out = (float*)d_out;

    // workspace layout (floats)
    float* gi = (float*)d_ws;                  // N_T * 384
    float* Mt = gi + (size_t)N_T * S3;         // 128 * 384
    float* b2 = Mt + (size_t)S * S3;           // 384
    float* mc = b2 + S3;                       // 384
    unsigned* Whh16 = (unsigned*)(mc + S3);    // 384 * 64 packed f16 pairs

    prep_kernel<<<S3, S, 0, stream>>>(w_ih, b_ih, b_hh, proj_w, proj_b, Mt, b2, mc);
    wcvt_kernel<<<S3, 64, 0, stream>>>(w_hh, Whh16);
    gi_kernel<<<N_T / TB, S3, 0, stream>>>(evs, Mt, b2, mc, gi);
    scan_kernel<<<1, THREADS, 0, stream>>>(gi, Whh16, h0, b_hh,
                                           final_w, final_b, out);
}